// Round 1
// baseline (1960.603 us; speedup 1.0000x reference)
//
#include <hip/hip_runtime.h>
#include <hip/hip_bf16.h>

// BiLSTM: B=64, T=2048, F=128, U=128. fp32 in/out.
// Phase 1: Zx[d][t][b][4U] = x[b,t,:] @ W_d[0:128,:] + b_d   (f16, in d_ws: 256 MiB)
// Phase 2: 32 persistent workgroups (2 dirs x 16 batch-groups of 4), each runs the
//          2048-step recurrence with Wh (W_d[128:256,:]) as f16 MFMA B-fragments in VGPRs.

typedef _Float16 half8_t __attribute__((ext_vector_type(8)));
typedef _Float16 half4_t __attribute__((ext_vector_type(4)));
typedef float floatx4 __attribute__((ext_vector_type(4)));

#define T_SEQ 2048
#define NBATCH 64
#define GDIM 512

__device__ __forceinline__ float sigm_f(float x) {
    return __builtin_amdgcn_rcpf(1.0f + __expf(-x));
}
__device__ __forceinline__ float tanh_f(float x) {
    // tanh(x) = 1 - 2/(exp(2x)+1); saturates correctly at +-1 for large |x|
    return 1.0f - 2.0f * __builtin_amdgcn_rcpf(1.0f + __expf(2.0f * x));
}

// ---------------- Phase 1: Zx GEMM ----------------
// grid: (128 = 32 t-tiles x 4 c-tiles, 64 batches, 2 dirs), block 256 (4 waves)
// per wg: A-tile 64x128 (x rows), B-tile 128x128 (W cols), f16 MFMA 16x16x32.
__global__ __launch_bounds__(256) void zx_gemm(
    const float* __restrict__ x,
    const float* __restrict__ Wfw, const float* __restrict__ bfw,
    const float* __restrict__ Wbw, const float* __restrict__ bbw,
    _Float16* __restrict__ zx) {
    const int tid = threadIdx.x;
    const int ttile = blockIdx.x >> 2;   // 0..31
    const int ctile = blockIdx.x & 3;    // 0..3
    const int by = blockIdx.y;           // batch
    const int d = blockIdx.z;            // dir
    const int t0 = ttile * 64;
    const int c0 = ctile * 128;
    const float* W = d ? Wbw : Wfw;
    const float* bias = d ? bbw : bfw;

    // k-stride 136 f16 (272B, 16B-aligned): conflict-free b128 fragment reads
    __shared__ _Float16 lA[64 * 136];
    __shared__ _Float16 lB[128 * 136];

    // stage A = x[by, t0..t0+63, 0..127] -> lA[row][k]
    const float* xp = x + ((size_t)by * T_SEQ + t0) * 128;
    for (int i = 0; i < 8; ++i) {
        int v = i * 256 + tid;           // 0..2047 float4s
        int r = v >> 5;                  // row 0..63
        int kq = (v & 31) << 2;          // k 0,4,..124
        float4 f = *(const float4*)(xp + r * 128 + kq);
        half4_t h4;
        h4[0] = (_Float16)f.x; h4[1] = (_Float16)f.y;
        h4[2] = (_Float16)f.z; h4[3] = (_Float16)f.w;
        *(half4_t*)&lA[r * 136 + kq] = h4;
    }
    // stage B = W[0..127, c0..c0+127] transposed -> lB[col][k]
    const float* wp = W + c0;
    for (int i = 0; i < 16; ++i) {
        int v = i * 256 + tid;           // 0..4095 float4s
        int k = v >> 5;                  // 0..127
        int cq = (v & 31) << 2;          // 0,4,..124
        float4 f = *(const float4*)(wp + (size_t)k * GDIM + cq);
        lB[(cq + 0) * 136 + k] = (_Float16)f.x;
        lB[(cq + 1) * 136 + k] = (_Float16)f.y;
        lB[(cq + 2) * 136 + k] = (_Float16)f.z;
        lB[(cq + 3) * 136 + k] = (_Float16)f.w;
    }
    __syncthreads();

    const int w = tid >> 6, lane = tid & 63, lm = lane & 15, q = lane >> 4;
    floatx4 acc[8];
#pragma unroll
    for (int nt = 0; nt < 8; ++nt) acc[nt] = (floatx4){0.f, 0.f, 0.f, 0.f};
#pragma unroll
    for (int ks = 0; ks < 4; ++ks) {
        const int k0 = ks * 32 + q * 8;
        half8_t a = *(const half8_t*)&lA[(w * 16 + lm) * 136 + k0];
#pragma unroll
        for (int nt = 0; nt < 8; ++nt) {
            half8_t b = *(const half8_t*)&lB[(nt * 16 + lm) * 136 + k0];
            acc[nt] = __builtin_amdgcn_mfma_f32_16x16x32_f16(a, b, acc[nt], 0, 0, 0);
        }
    }
    // epilogue: +bias, store f16 to zx[d][t][b][c]
#pragma unroll
    for (int nt = 0; nt < 8; ++nt) {
        int col = nt * 16 + lm;
        float bv = bias[c0 + col];
#pragma unroll
        for (int r = 0; r < 4; ++r) {
            int row = w * 16 + q * 4 + r;   // C/D: col=lane&15, row=(lane>>4)*4+reg
            size_t oi = (((size_t)d * T_SEQ + t0 + row) * NBATCH + by) * GDIM + c0 + col;
            zx[oi] = (_Float16)(acc[nt][r] + bv);
        }
    }
}

// ---------------- Phase 2: recurrence ----------------
// grid: (16 batch-groups, 2 dirs), block 512 (8 waves). Each wave owns 64 gate cols.
__global__ __launch_bounds__(512) void lstm_rec(
    const float* __restrict__ Wfw, const float* __restrict__ Wbw,
    const _Float16* __restrict__ zx, float* __restrict__ out) {
    const int bg = blockIdx.x;            // 0..15
    const int d = blockIdx.y;             // 0..1
    const int b0 = bg * 4;
    const float* Wd = d ? Wbw : Wfw;
    const int tid = threadIdx.x;
    const int w = tid >> 6, lane = tid & 63, lm = lane & 15, q = lane >> 4;

    __shared__ _Float16 hA[16 * 136];     // A-tile: h for 4 real batches (rows 0-3), pad rows 0
    __shared__ float zL[4 * GDIM];        // z exchange: [m][gate][u]

    // load Wh B-fragments (rows 128..255 of W) into VGPRs, f16. 16 frags = 64 VGPRs.
    half8_t bfr[4][4];
#pragma unroll
    for (int ks = 0; ks < 4; ++ks)
#pragma unroll
        for (int nt = 0; nt < 4; ++nt) {
            int n_g = w * 64 + nt * 16 + lm;
            int kb = 128 + ks * 32 + q * 8;
            half8_t f;
#pragma unroll
            for (int j = 0; j < 8; ++j)
                f[j] = (_Float16)Wd[(size_t)(kb + j) * GDIM + n_g];
            bfr[ks][nt] = f;
        }

    for (int idx = tid; idx < 16 * 136; idx += 512) hA[idx] = (_Float16)0.f;
    __syncthreads();

    // gate-phase thread mapping: m = batch slot, u = hidden index (u-fast for coalescing)
    const int m = tid >> 7;               // 0..3
    const int u = tid & 127;              // 0..127
    float cst = 0.f;

    // prefetch Zx for step 0
    int tfirst = d ? (T_SEQ - 1) : 0;
    const _Float16* zp0 = zx + (((size_t)d * T_SEQ + tfirst) * NBATCH + b0 + m) * GDIM + u;
    _Float16 nz0 = zp0[0], nz1 = zp0[128], nz2 = zp0[256], nz3 = zp0[384];

    for (int s = 0; s < T_SEQ; ++s) {
        const int t = d ? (T_SEQ - 1 - s) : s;

        // A-fragments of h (rows 0-3 real, 4-15 zero)
        half8_t af[4];
#pragma unroll
        for (int ks = 0; ks < 4; ++ks)
            af[ks] = *(const half8_t*)&hA[lm * 136 + ks * 32 + q * 8];

        float z0 = (float)nz0, z1 = (float)nz1, z2 = (float)nz2, z3 = (float)nz3;
        if (s + 1 < T_SEQ) {  // prefetch next step's Zx
            int tn = d ? (T_SEQ - 2 - s) : (s + 1);
            const _Float16* p = zx + (((size_t)d * T_SEQ + tn) * NBATCH + b0 + m) * GDIM + u;
            nz0 = p[0]; nz1 = p[128]; nz2 = p[256]; nz3 = p[384];
        }

        floatx4 acc[4];
#pragma unroll
        for (int nt = 0; nt < 4; ++nt) acc[nt] = (floatx4){0.f, 0.f, 0.f, 0.f};
#pragma unroll
        for (int ks = 0; ks < 4; ++ks)
#pragma unroll
            for (int nt = 0; nt < 4; ++nt)
                acc[nt] = __builtin_amdgcn_mfma_f32_16x16x32_f16(af[ks], bfr[ks][nt], acc[nt], 0, 0, 0);

        // lanes 0-15 hold batches 0-3 (rows = regs 0-3); scatter z to zL[m][g][u]
        if (q == 0) {
#pragma unroll
            for (int nt = 0; nt < 4; ++nt) {
                int c = w * 64 + nt * 16 + lm;
                int g = c >> 7, uu = c & 127;
#pragma unroll
                for (int r = 0; r < 4; ++r)
                    zL[(r * 4 + g) * 128 + uu] = acc[nt][r];
            }
        }
        __syncthreads();   // z visible

        float zi = zL[(m * 4 + 0) * 128 + u] + z0;
        float zj = zL[(m * 4 + 1) * 128 + u] + z1;
        float zf = zL[(m * 4 + 2) * 128 + u] + z2;
        float zo = zL[(m * 4 + 3) * 128 + u] + z3;
        cst = cst * sigm_f(zf + 1.0f) + sigm_f(zi) * tanh_f(zj);   // FORGET_BIAS=1
        float h = sigm_f(zo) * tanh_f(cst);
        hA[m * 136 + u] = (_Float16)h;
        out[(((size_t)(b0 + m)) * T_SEQ + t) * 256 + d * 128 + u] = h;
        __syncthreads();   // h visible before next A-frag read / zL overwrite
    }
}

extern "C" void kernel_launch(void* const* d_in, const int* in_sizes, int n_in,
                              void* d_out, int out_size, void* d_ws, size_t ws_size,
                              hipStream_t stream) {
    const float* x   = (const float*)d_in[0];
    const float* Wfw = (const float*)d_in[1];
    const float* bfw = (const float*)d_in[2];
    const float* Wbw = (const float*)d_in[3];
    const float* bbw = (const float*)d_in[4];
    float* out = (float*)d_out;
    _Float16* zx = (_Float16*)d_ws;  // needs 2*2048*64*512*2B = 256 MiB

    dim3 g1(128, 64, 2);
    zx_gemm<<<g1, 256, 0, stream>>>(x, Wfw, bfw, Wbw, bbw, zx);
    dim3 g2(16, 2);
    lstm_rec<<<g2, 512, 0, stream>>>(Wfw, Wbw, zx, out);
}

// Round 2
// 1640.280 us; speedup vs baseline: 1.1953x; 1.1953x over previous
//
#include <hip/hip_runtime.h>
#include <hip/hip_bf16.h>

// BiLSTM: B=64, T=2048, F=128, U=128. fp32 in/out.
// Phase 1: zx[d][bg][t][g][w][L] (f16) = x@Wx + b, L = m*16+ulocal (m=b&3).
// Phase 2: 32 WGs (2 dir x 16 batch-groups of 4), 8 waves each; per step ONE
//          lgkm-only barrier (inline asm) so zx prefetch stays in flight.
//          In-wave gates + row-replicated h => no z exchange, 1 cell/lane.

typedef _Float16 half8_t __attribute__((ext_vector_type(8)));
typedef _Float16 half4_t __attribute__((ext_vector_type(4)));
typedef float floatx4 __attribute__((ext_vector_type(4)));

#define T_SEQ 2048
#define GDIM 512

__device__ __forceinline__ float sigm_f(float x) {
    return __builtin_amdgcn_rcpf(1.0f + __expf(-x));
}
__device__ __forceinline__ float tanh_f(float x) {
    return 1.0f - 2.0f * __builtin_amdgcn_rcpf(1.0f + __expf(2.0f * x));
}
__device__ __forceinline__ float sel4(floatx4 v, int m) {
    float a = (m & 1) ? v[1] : v[0];
    float b = (m & 1) ? v[3] : v[2];
    return (m & 2) ? b : a;
}

// ---------------- Phase 1: Zx GEMM ----------------
// grid: (32 ttiles, 64 batches, 2 dirs), block 256. A staged once; 4 ctile passes.
__global__ __launch_bounds__(256) void zx_gemm(
    const float* __restrict__ x,
    const float* __restrict__ Wfw, const float* __restrict__ bfw,
    const float* __restrict__ Wbw, const float* __restrict__ bbw,
    _Float16* __restrict__ zx) {
    const int tid = threadIdx.x;
    const int tt = blockIdx.x;           // 0..31
    const int b = blockIdx.y;            // batch
    const int d = blockIdx.z;            // dir
    const int t0 = tt * 64;
    const float* W = d ? Wbw : Wfw;
    const float* bias = d ? bbw : bfw;
    const int bg = b >> 2, m = b & 3;

    __shared__ _Float16 lA[64 * 136];
    __shared__ _Float16 lB[128 * 136];

    // stage A = x[b, t0..t0+63, 0..127] -> lA[row][k]
    const float* xp = x + ((size_t)b * T_SEQ + t0) * 128;
    for (int i = 0; i < 8; ++i) {
        int v = i * 256 + tid;
        int r = v >> 5;
        int kq = (v & 31) << 2;
        float4 f = *(const float4*)(xp + r * 128 + kq);
        half4_t h4;
        h4[0] = (_Float16)f.x; h4[1] = (_Float16)f.y;
        h4[2] = (_Float16)f.z; h4[3] = (_Float16)f.w;
        *(half4_t*)&lA[r * 136 + kq] = h4;
    }

    const int w1 = tid >> 6, lane = tid & 63, lm = lane & 15, q = lane >> 4;

    for (int ct = 0; ct < 4; ++ct) {
        // stage B = W[0..127, ct*128 .. +128) transposed -> lB[col][k]
        const float* wp = W + ct * 128;
        for (int i = 0; i < 16; ++i) {
            int v = i * 256 + tid;
            int k = v >> 5;
            int cq = (v & 31) << 2;
            float4 f = *(const float4*)(wp + (size_t)k * GDIM + cq);
            lB[(cq + 0) * 136 + k] = (_Float16)f.x;
            lB[(cq + 1) * 136 + k] = (_Float16)f.y;
            lB[(cq + 2) * 136 + k] = (_Float16)f.z;
            lB[(cq + 3) * 136 + k] = (_Float16)f.w;
        }
        __syncthreads();

        floatx4 acc[8];
#pragma unroll
        for (int nt = 0; nt < 8; ++nt) acc[nt] = (floatx4){0.f, 0.f, 0.f, 0.f};
#pragma unroll
        for (int ks = 0; ks < 4; ++ks) {
            const int k0 = ks * 32 + q * 8;
            half8_t a = *(const half8_t*)&lA[(w1 * 16 + lm) * 136 + k0];
#pragma unroll
            for (int nt = 0; nt < 8; ++nt) {
                half8_t bf = *(const half8_t*)&lB[(nt * 16 + lm) * 136 + k0];
                acc[nt] = __builtin_amdgcn_mfma_f32_16x16x32_f16(a, bf, acc[nt], 0, 0, 0);
            }
        }
        // store: g = ct; value (t, b, c = ct*128 + nt*16 + lm)
        // addr f16: (((d*16+bg)*T + t)*4 + ct)*512 + nt*64 + m*16 + lm
#pragma unroll
        for (int nt = 0; nt < 8; ++nt) {
            float bv = bias[ct * 128 + nt * 16 + lm];
#pragma unroll
            for (int rr = 0; rr < 4; ++rr) {
                int t = t0 + w1 * 16 + q * 4 + rr;
                size_t oi = (((size_t)(d * 16 + bg) * T_SEQ + t) * 4 + ct) * 512
                            + nt * 64 + m * 16 + lm;
                zx[oi] = (_Float16)(acc[nt][rr] + bv);
            }
        }
        __syncthreads();   // before restaging lB
    }
}

// ---------------- Phase 2: recurrence ----------------
// grid: (16 batch-groups, 2 dirs), block 512 (8 waves).
// Wave w owns cols {g*128 + w*16 + lm}, g=0..3 (in-wave gates).
__global__ __launch_bounds__(512) void lstm_rec(
    const float* __restrict__ Wfw, const float* __restrict__ Wbw,
    const _Float16* __restrict__ zx, float* __restrict__ out) {
    const int bg = blockIdx.x;            // 0..15
    const int d = blockIdx.y;             // 0..1
    const int b0 = bg * 4;
    const float* Wd = d ? Wbw : Wfw;
    const int tid = threadIdx.x;
    const int w = tid >> 6, lane = tid & 63, lm = lane & 15, q = lane >> 4;
    const int m = q;                      // batch slot this lane's gate cell uses

    __shared__ _Float16 hbuf[2][4 * 136]; // double-buffered h, rows = batch 0..3

    // Wh B-fragments: bfr[g][ks], col = g*128 + w*16 + lm, k = 128 + ks*32 + q*8 + j
    half8_t bfr[4][4];
#pragma unroll
    for (int g = 0; g < 4; ++g)
#pragma unroll
        for (int ks = 0; ks < 4; ++ks) {
            int col = g * 128 + w * 16 + lm;
            int kb = 128 + ks * 32 + q * 8;
            half8_t f;
#pragma unroll
            for (int j = 0; j < 8; ++j)
                f[j] = (_Float16)Wd[(size_t)(kb + j) * GDIM + col];
            bfr[g][ks] = f;
        }

    for (int i = tid; i < 2 * 4 * 136; i += 512) ((_Float16*)hbuf)[i] = (_Float16)0.f;

    // zx prefetch pipeline, depth 2. Layout: [d*16+bg][t][g][w][lane] f16.
    const _Float16* zb = zx + (size_t)(d * 16 + bg) * T_SEQ * 2048 + w * 64 + lane;
    _Float16 n1[4], n2[4];
    {
        int ta = d ? (T_SEQ - 1) : 0;
        int tb = d ? (T_SEQ - 2) : 1;
#pragma unroll
        for (int g = 0; g < 4; ++g) n1[g] = zb[(size_t)ta * 2048 + g * 512];
#pragma unroll
        for (int g = 0; g < 4; ++g) n2[g] = zb[(size_t)tb * 2048 + g * 512];
    }
    float cst = 0.f;
    __syncthreads();

    for (int s = 0; s < T_SEQ; ++s) {
        const int t = d ? (T_SEQ - 1 - s) : s;
        const _Float16* hr = hbuf[s & 1];
        _Float16* hw = hbuf[(s + 1) & 1];

        // A-fragments: A[row][k] = h[row&3][k] (row-replicated)
        half8_t af[4];
#pragma unroll
        for (int ks = 0; ks < 4; ++ks)
            af[ks] = *(const half8_t*)&hr[(lm & 3) * 136 + ks * 32 + q * 8];

        // rotate zx pipeline; issue prefetch for s+2 (stays in flight across barrier)
        float zc[4];
#pragma unroll
        for (int g = 0; g < 4; ++g) { zc[g] = (float)n1[g]; n1[g] = n2[g]; }
        int sn = (s + 2 < T_SEQ) ? s + 2 : T_SEQ - 1;
        int tn = d ? (T_SEQ - 1 - sn) : sn;
#pragma unroll
        for (int g = 0; g < 4; ++g) n2[g] = zb[(size_t)tn * 2048 + g * 512];

        floatx4 acg[4];
#pragma unroll
        for (int g = 0; g < 4; ++g) acg[g] = (floatx4){0.f, 0.f, 0.f, 0.f};
#pragma unroll
        for (int ks = 0; ks < 4; ++ks)
#pragma unroll
            for (int g = 0; g < 4; ++g)
                acg[g] = __builtin_amdgcn_mfma_f32_16x16x32_f16(af[ks], bfr[g][ks], acg[g], 0, 0, 0);

        // every lane: one cell (batch m = q, u = w*16 + lm); regs hold all 4 batches
        float zi = sel4(acg[0], m) + zc[0];
        float zj = sel4(acg[1], m) + zc[1];
        float zf = sel4(acg[2], m) + zc[2];
        float zo = sel4(acg[3], m) + zc[3];
        cst = cst * sigm_f(zf + 1.0f) + sigm_f(zi) * tanh_f(zj);
        float h = sigm_f(zo) * tanh_f(cst);

        hw[m * 136 + w * 16 + lm] = (_Float16)h;
        out[((size_t)(b0 + m) * T_SEQ + t) * 256 + d * 128 + w * 16 + lm] = h;

        // LDS-only barrier: drain lgkm (h write) but leave vmcnt (zx prefetch,
        // out stores) in flight.
        asm volatile("s_waitcnt lgkmcnt(0)\n\ts_barrier" ::: "memory");
    }
}

extern "C" void kernel_launch(void* const* d_in, const int* in_sizes, int n_in,
                              void* d_out, int out_size, void* d_ws, size_t ws_size,
                              hipStream_t stream) {
    const float* x   = (const float*)d_in[0];
    const float* Wfw = (const float*)d_in[1];
    const float* bfw = (const float*)d_in[2];
    const float* Wbw = (const float*)d_in[3];
    const float* bbw = (const float*)d_in[4];
    float* out = (float*)d_out;
    _Float16* zx = (_Float16*)d_ws;  // 2*16*2048*2048*2B = 256 MiB

    dim3 g1(32, 64, 2);
    zx_gemm<<<g1, 256, 0, stream>>>(x, Wfw, bfw, Wbw, bbw, zx);
    dim3 g2(16, 2);
    lstm_rec<<<g2, 512, 0, stream>>>(Wfw, Wbw, zx, out);
}